// Round 1
// baseline (2089.890 us; speedup 1.0000x reference)
//
#include <hip/hip_runtime.h>
#include <math.h>

#define ISQ2 0.70710678118654752440f

static __device__ __constant__ float H0c[13] = {
    -0.0017578f, 0.0f, 0.0222656f, -0.046875f, -0.0482422f, 0.296875f,
    0.5554688f, 0.296875f, -0.0482422f, -0.046875f, 0.0222656f, 0.0f, -0.0017578f};
static __device__ __constant__ float H1c[19] = {
    -7.06e-05f, 0.0f, 0.0013419f, -0.0018834f, -0.0071568f, 0.023856f,
    0.0556431f, -0.0516881f, -0.2997576f, 0.5594308f, -0.2997576f, -0.0516881f,
    0.0556431f, 0.023856f, -0.0071568f, -0.0018834f, 0.0013419f, 0.0f, -7.06e-05f};

__device__ __forceinline__ int refl32(int i) {
    if (i < 0) i = -1 - i;
    if (i > 31) i = 63 - i;
    return i;
}

__device__ __forceinline__ float gelu_exact(float x) {
    return 0.5f * x * (1.0f + erff(x * ISQ2));
}

// ---------------- K1: LN1 + transpose (B,N,C)->(B,C,32,32) ----------------
__global__ __launch_bounds__(256) void k_ln1_t(const float* __restrict__ x,
                                               const float* __restrict__ g,
                                               const float* __restrict__ be,
                                               float* __restrict__ A) {
    __shared__ float sx[64][65];
    __shared__ float rs[64][4], rq[64][4];
    __shared__ float sm[64], sv[64];
    int b = blockIdx.x >> 4;
    int n0 = (blockIdx.x & 15) << 6;
    int tid = threadIdx.x;
    const float* xp = x + ((size_t)b * 1024 + n0) * 64;
#pragma unroll
    for (int rep = 0; rep < 16; ++rep) {
        int idx = rep * 256 + tid;
        sx[idx >> 6][idx & 63] = xp[idx];
    }
    __syncthreads();
    {
        int i = tid >> 2, q = tid & 3;
        float s = 0.f, ss = 0.f;
#pragma unroll
        for (int d = 0; d < 16; ++d) {
            float v = sx[i][q * 16 + d];
            s += v; ss += v * v;
        }
        rs[i][q] = s; rq[i][q] = ss;
    }
    __syncthreads();
    if (tid < 64) {
        float s = rs[tid][0] + rs[tid][1] + rs[tid][2] + rs[tid][3];
        float ss = rq[tid][0] + rq[tid][1] + rq[tid][2] + rq[tid][3];
        float m = s * (1.f / 64.f);
        float v = ss * (1.f / 64.f) - m * m;
        sm[tid] = m;
        sv[tid] = rsqrtf(v + 1e-5f);
    }
    __syncthreads();
#pragma unroll
    for (int rep = 0; rep < 16; ++rep) {
        int idx = rep * 256 + tid;
        int c = idx >> 6, i = idx & 63;
        float val = (sx[i][c] - sm[i]) * sv[i] * g[c] + be[c];
        A[((size_t)(b * 64 + c)) * 1024 + n0 + i] = val;
    }
}

// ---------------- K2: forward DTCWT per (b,c) image ----------------
__device__ __forceinline__ float col19(const float (*arr)[33], int h, int w) {
    float s = 0.f;
#pragma unroll
    for (int k = 0; k < 19; ++k) s += H1c[k] * arr[refl32(h + k - 9)][w];
    return s;
}
__device__ __forceinline__ float col13(const float (*arr)[33], int h, int w) {
    float s = 0.f;
#pragma unroll
    for (int k = 0; k < 13; ++k) s += H0c[k] * arr[refl32(h + k - 6)][w];
    return s;
}

__global__ __launch_bounds__(256) void k_fwd(const float* __restrict__ A,
                                             const float* __restrict__ wll,
                                             float* __restrict__ LL,
                                             float* __restrict__ HSr,
                                             float* __restrict__ HSi) {
    __shared__ float sx[32][33], slo[32][33], shi[32][33];
    int bc = blockIdx.x;
    int c = bc & 63;
    int tid = threadIdx.x;
    const float* ap = A + (size_t)bc * 1024;
#pragma unroll
    for (int r = 0; r < 4; ++r) {
        int p = r * 256 + tid;
        sx[p >> 5][p & 31] = ap[p];
    }
    __syncthreads();
#pragma unroll
    for (int r = 0; r < 4; ++r) {
        int p = r * 256 + tid;
        int h = p >> 5, w = p & 31;
        float lo = 0.f, hi = 0.f;
#pragma unroll
        for (int k = 0; k < 13; ++k) lo += H0c[k] * sx[h][refl32(w + k - 6)];
#pragma unroll
        for (int k = 0; k < 19; ++k) hi += H1c[k] * sx[h][refl32(w + k - 9)];
        slo[h][w] = lo;
        shi[h][w] = hi;
    }
    __syncthreads();
    // LL = H0 columns on lo, * w_ll
#pragma unroll
    for (int r = 0; r < 4; ++r) {
        int p = r * 256 + tid;
        int h = p >> 5, w = p & 31;
        float acc = 0.f;
#pragma unroll
        for (int k = 0; k < 13; ++k) acc += H0c[k] * slo[refl32(h + k - 6)][w];
        LL[(size_t)bc * 1024 + p] = acc * wll[c * 1024 + p];
    }
    // subbands via q2c
    {
        int p = tid;  // 0..255
        int i = p >> 4, j = p & 15;
        int h0 = 2 * i, w0 = 2 * j;
        size_t base = (size_t)bc * 1536 + p;
        float a, bb, cc, dd;
        // lh (H1 cols on lo) -> orientations 0 (d15), 5 (d165)
        a = col19(slo, h0, w0); bb = col19(slo, h0, w0 + 1);
        cc = col19(slo, h0 + 1, w0); dd = col19(slo, h0 + 1, w0 + 1);
        HSr[base + 0 * 256] = (a - dd) * ISQ2; HSi[base + 0 * 256] = (bb + cc) * ISQ2;
        HSr[base + 5 * 256] = (a + dd) * ISQ2; HSi[base + 5 * 256] = (bb - cc) * ISQ2;
        // hh (H1 cols on hi) -> orientations 1 (d45), 4 (d135)
        a = col19(shi, h0, w0); bb = col19(shi, h0, w0 + 1);
        cc = col19(shi, h0 + 1, w0); dd = col19(shi, h0 + 1, w0 + 1);
        HSr[base + 1 * 256] = (a - dd) * ISQ2; HSi[base + 1 * 256] = (bb + cc) * ISQ2;
        HSr[base + 4 * 256] = (a + dd) * ISQ2; HSi[base + 4 * 256] = (bb - cc) * ISQ2;
        // hl (H0 cols on hi) -> orientations 2 (d75), 3 (d105)
        a = col13(shi, h0, w0); bb = col13(shi, h0, w0 + 1);
        cc = col13(shi, h0 + 1, w0); dd = col13(shi, h0 + 1, w0 + 1);
        HSr[base + 2 * 256] = (a - dd) * ISQ2; HSi[base + 2 * 256] = (bb + cc) * ISQ2;
        HSr[base + 3 * 256] = (a + dd) * ISQ2; HSi[base + 3 * 256] = (bb - cc) * ISQ2;
    }
}

// ---------------- K3: complex block-diagonal MLP (in-place on HS) ----------------
__global__ __launch_bounds__(256) void k_mlp(float* __restrict__ HSr,
                                             float* __restrict__ HSi,
                                             const float* __restrict__ w1,
                                             const float* __restrict__ w2,
                                             const float* __restrict__ b1,
                                             const float* __restrict__ b2) {
    __shared__ float sr[64][65], si[64][65];
    __shared__ float w1s[2048], w2s[2048], b1s[128], b2s[128];
    int blk = blockIdx.x;  // B*6*4 = 6144
    int b = blk / 24;
    int rem = blk % 24;
    int o = rem >> 2;
    int ij0 = (rem & 3) << 6;
    int tid = threadIdx.x;
    for (int idx = tid; idx < 2048; idx += 256) {
        w1s[idx] = w1[idx];
        w2s[idx] = w2[idx];
    }
    if (tid < 128) { b1s[tid] = b1[tid]; b2s[tid] = b2[tid]; }
#pragma unroll
    for (int rep = 0; rep < 16; ++rep) {
        int idx = rep * 256 + tid;
        int c = idx >> 6, j = idx & 63;
        size_t gi = ((size_t)(b * 64 + c) * 6 + o) * 256 + ij0 + j;
        sr[c][j] = HSr[gi];
        si[c][j] = HSi[gi];
    }
    __syncthreads();
    {
        int j = tid & 63, q = tid >> 6;  // q = channel block 0..3
        float xr[16], xi[16];
#pragma unroll
        for (int d = 0; d < 16; ++d) {
            xr[d] = sr[q * 16 + d][j];
            xi[d] = si[q * 16 + d][j];
        }
        float r1[16], i1[16];
#pragma unroll
        for (int k = 0; k < 16; ++k) {
            float ar = b1s[q * 16 + k];
            float ai = b1s[64 + q * 16 + k];
#pragma unroll
            for (int d = 0; d < 16; ++d) {
                float wr = w1s[q * 256 + d * 16 + k];
                float wi = w1s[1024 + q * 256 + d * 16 + k];
                ar += xr[d] * wr - xi[d] * wi;
                ai += xr[d] * wi + xi[d] * wr;
            }
            r1[k] = fmaxf(ar, 0.f);
            i1[k] = fmaxf(ai, 0.f);
        }
#pragma unroll
        for (int k = 0; k < 16; ++k) {
            float ar = b2s[q * 16 + k];
            float ai = b2s[64 + q * 16 + k];
#pragma unroll
            for (int d = 0; d < 16; ++d) {
                float wr = w2s[q * 256 + d * 16 + k];
                float wi = w2s[1024 + q * 256 + d * 16 + k];
                ar += r1[d] * wr - i1[d] * wi;
                ai += r1[d] * wi + i1[d] * wr;
            }
            sr[q * 16 + k][j] = ar;
            si[q * 16 + k][j] = ai;
        }
    }
    __syncthreads();
#pragma unroll
    for (int rep = 0; rep < 16; ++rep) {
        int idx = rep * 256 + tid;
        int c = idx >> 6, j = idx & 63;
        size_t gi = ((size_t)(b * 64 + c) * 6 + o) * 256 + ij0 + j;
        HSr[gi] = sr[c][j];
        HSi[gi] = si[c][j];
    }
}

// ---------------- K4: inverse DTCWT per (b,c) -> Y (B,C,N) ----------------
__global__ __launch_bounds__(256) void k_inv(const float* __restrict__ LL,
                                             const float* __restrict__ HSr,
                                             const float* __restrict__ HSi,
                                             float* __restrict__ Y) {
    __shared__ float sll[32][33], slh[32][33], shl[32][33], shh[32][33];
    __shared__ float slo[32][33], shi[32][33];
    int bc = blockIdx.x;
    int tid = threadIdx.x;
    const float* lp = LL + (size_t)bc * 1024;
#pragma unroll
    for (int r = 0; r < 4; ++r) {
        int p = r * 256 + tid;
        sll[p >> 5][p & 31] = lp[p];
    }
    {
        int p = tid;
        int i = p >> 4, j = p & 15;
        int h0 = 2 * i, w0 = 2 * j;
        size_t base = (size_t)bc * 1536 + p;
        float o0r = HSr[base + 0 * 256], o0i = HSi[base + 0 * 256];
        float o1r = HSr[base + 1 * 256], o1i = HSi[base + 1 * 256];
        float o2r = HSr[base + 2 * 256], o2i = HSi[base + 2 * 256];
        float o3r = HSr[base + 3 * 256], o3i = HSi[base + 3 * 256];
        float o4r = HSr[base + 4 * 256], o4i = HSi[base + 4 * 256];
        float o5r = HSr[base + 5 * 256], o5i = HSi[base + 5 * 256];
        // lh = c2q(o0,o5)
        slh[h0][w0] = (o0r + o5r) * ISQ2;
        slh[h0][w0 + 1] = (o0i + o5i) * ISQ2;
        slh[h0 + 1][w0] = (o0i - o5i) * ISQ2;
        slh[h0 + 1][w0 + 1] = (o5r - o0r) * ISQ2;
        // hl = c2q(o2,o3)
        shl[h0][w0] = (o2r + o3r) * ISQ2;
        shl[h0][w0 + 1] = (o2i + o3i) * ISQ2;
        shl[h0 + 1][w0] = (o2i - o3i) * ISQ2;
        shl[h0 + 1][w0 + 1] = (o3r - o2r) * ISQ2;
        // hh = c2q(o1,o4)
        shh[h0][w0] = (o1r + o4r) * ISQ2;
        shh[h0][w0 + 1] = (o1i + o4i) * ISQ2;
        shh[h0 + 1][w0] = (o1i - o4i) * ISQ2;
        shh[h0 + 1][w0 + 1] = (o4r - o1r) * ISQ2;
    }
    __syncthreads();
#pragma unroll
    for (int r = 0; r < 4; ++r) {
        int p = r * 256 + tid;
        int h = p >> 5, w = p & 31;
        float lo = 0.f, hi = 0.f;
#pragma unroll
        for (int k = 0; k < 19; ++k) {
            float g0 = (k & 1) ? H1c[k] : -H1c[k];
            int hh2 = refl32(h + k - 9);
            lo += g0 * sll[hh2][w];
            hi += g0 * shl[hh2][w];
        }
#pragma unroll
        for (int k = 0; k < 13; ++k) {
            float g1 = (k & 1) ? H0c[k] : -H0c[k];
            int hh2 = refl32(h + k - 6);
            lo += g1 * slh[hh2][w];
            hi += g1 * shh[hh2][w];
        }
        slo[h][w] = lo;
        shi[h][w] = hi;
    }
    __syncthreads();
#pragma unroll
    for (int r = 0; r < 4; ++r) {
        int p = r * 256 + tid;
        int h = p >> 5, w = p & 31;
        float y = 0.f;
#pragma unroll
        for (int k = 0; k < 19; ++k) {
            float g0 = (k & 1) ? H1c[k] : -H1c[k];
            y += g0 * slo[h][refl32(w + k - 9)];
        }
#pragma unroll
        for (int k = 0; k < 13; ++k) {
            float g1 = (k & 1) ? H0c[k] : -H0c[k];
            y += g1 * shi[h][refl32(w + k - 6)];
        }
        Y[(size_t)bc * 1024 + p] = y;
    }
}

// ---------------- K4b: X1 = x + Y^T -> d_out (B,N,C) ----------------
__global__ __launch_bounds__(256) void k_addt(const float* __restrict__ Y,
                                              const float* __restrict__ x,
                                              float* __restrict__ out) {
    __shared__ float sy[64][65];
    int b = blockIdx.x >> 4;
    int n0 = (blockIdx.x & 15) << 6;
    int tid = threadIdx.x;
#pragma unroll
    for (int rep = 0; rep < 16; ++rep) {
        int idx = rep * 256 + tid;
        int c = idx >> 6, i = idx & 63;
        sy[c][i] = Y[((size_t)(b * 64 + c)) * 1024 + n0 + i];
    }
    __syncthreads();
#pragma unroll
    for (int rep = 0; rep < 16; ++rep) {
        int idx = rep * 256 + tid;
        int i = idx >> 6, c = idx & 63;
        size_t gi = ((size_t)b * 1024 + n0 + i) * 64 + c;
        out[gi] = x[gi] + sy[c][i];
    }
}

// ---------------- K5: LN2 + lin1 + GELU -> H1 (B,N,256) ----------------
__global__ __launch_bounds__(256) void k_leff1(const float* __restrict__ X1,
                                               const float* __restrict__ g2,
                                               const float* __restrict__ be2,
                                               const float* __restrict__ W1,
                                               const float* __restrict__ B1,
                                               float* __restrict__ H1) {
    __shared__ float sh[32][64];
    __shared__ float w1s[64 * 256];
    int b = blockIdx.x >> 5;
    int t0 = (blockIdx.x & 31) << 5;  // 32 tokens
    int tid = threadIdx.x;
    for (int idx = tid; idx < 16384; idx += 256) w1s[idx] = W1[idx];
    int wv = tid >> 6, l = tid & 63;
#pragma unroll
    for (int r2 = 0; r2 < 8; ++r2) {
        int tok = r2 * 4 + wv;
        float v = X1[((size_t)b * 1024 + t0 + tok) * 64 + l];
        float s = v, ss = v * v;
#pragma unroll
        for (int off = 32; off; off >>= 1) {
            s += __shfl_xor(s, off, 64);
            ss += __shfl_xor(ss, off, 64);
        }
        float m = s * (1.f / 64.f);
        float var = ss * (1.f / 64.f) - m * m;
        sh[tok][l] = (v - m) * rsqrtf(var + 1e-5f) * g2[l] + be2[l];
    }
    __syncthreads();
    float bias = B1[tid];
    for (int tok = 0; tok < 32; ++tok) {
        float acc = bias;
#pragma unroll 8
        for (int d = 0; d < 64; ++d) acc += sh[tok][d] * w1s[d * 256 + tid];
        H1[((size_t)b * 1024 + t0 + tok) * 256 + tid] = gelu_exact(acc);
    }
}

// ---------------- K6: dwconv3x3 + GELU + lin2 + residual -> out ----------------
__global__ __launch_bounds__(256) void k_leff2(const float* __restrict__ H1,
                                               const float* __restrict__ DW,
                                               const float* __restrict__ DB,
                                               const float* __restrict__ W2,
                                               const float* __restrict__ B2,
                                               float* __restrict__ out) {
    __shared__ float sg[16][256];
    __shared__ float w2s[256 * 64];
    int blk = blockIdx.x;  // 16384
    int b = blk >> 6;
    int seg = blk & 63;
    int h = seg >> 1;
    int w0 = (seg & 1) << 4;
    int tid = threadIdx.x;
    for (int idx = tid; idx < 16384; idx += 256) w2s[idx] = W2[idx];
    {
        float kern[9];
#pragma unroll
        for (int k = 0; k < 9; ++k) kern[k] = DW[tid * 9 + k];
        float bias = DB[tid];
        for (int tk = 0; tk < 16; ++tk) {
            int wc = w0 + tk;
            float acc = 0.f;
#pragma unroll
            for (int dh = -1; dh <= 1; ++dh) {
                int hh2 = h + dh;
                if (hh2 < 0 || hh2 > 31) continue;
#pragma unroll
                for (int dw2 = -1; dw2 <= 1; ++dw2) {
                    int ww = wc + dw2;
                    if (ww < 0 || ww > 31) continue;
                    acc += H1[((size_t)b * 1024 + hh2 * 32 + ww) * 256 + tid] *
                           kern[(dh + 1) * 3 + (dw2 + 1)];
                }
            }
            acc += bias;
            sg[tk][tid] = gelu_exact(acc);
        }
    }
    __syncthreads();
    {
        int c = tid & 63, ts = tid >> 6;
#pragma unroll
        for (int t2 = 0; t2 < 4; ++t2) {
            int tk = ts * 4 + t2;
            float acc = 0.f;
#pragma unroll 8
            for (int hid = 0; hid < 256; ++hid) acc += sg[tk][hid] * w2s[hid * 64 + c];
            size_t gi = ((size_t)b * 1024 + h * 32 + w0 + tk) * 64 + c;
            out[gi] = out[gi] + acc + B2[c];
        }
    }
}

extern "C" void kernel_launch(void* const* d_in, const int* in_sizes, int n_in,
                              void* d_out, int out_size, void* d_ws, size_t ws_size,
                              hipStream_t stream) {
    const float* x = (const float*)d_in[0];
    const float* ln1_g = (const float*)d_in[1];
    const float* ln1_b = (const float*)d_in[2];
    const float* w_ll = (const float*)d_in[3];
    const float* w1 = (const float*)d_in[4];
    const float* w2 = (const float*)d_in[5];
    const float* b1 = (const float*)d_in[6];
    const float* b2 = (const float*)d_in[7];
    const float* ln2_g = (const float*)d_in[8];
    const float* ln2_b = (const float*)d_in[9];
    const float* lin1_w = (const float*)d_in[10];
    const float* lin1_b = (const float*)d_in[11];
    const float* dw_w = (const float*)d_in[12];
    const float* dw_b = (const float*)d_in[13];
    const float* lin2_w = (const float*)d_in[14];
    const float* lin2_b = (const float*)d_in[15];
    float* out = (float*)d_out;
    char* ws = (char*)d_ws;

    // ws layout: A [0, 64MiB) ; HSr [64MiB, 160MiB) ; HSi [160MiB, 256MiB)
    // LL lives in d_out (dead until K4b overwrites it with X1).
    // H1 reuses ws [0, 256MiB) after the SVT path is done.
    float* A = (float*)ws;
    float* HSr = (float*)(ws + 67108864);
    float* HSi = (float*)(ws + 167772160);
    float* LL = out;
    float* Y = A;       // A is dead after k_fwd
    float* H1 = (float*)ws;  // entire 256MiB region, dead after k_addt

    k_ln1_t<<<dim3(4096), dim3(256), 0, stream>>>(x, ln1_g, ln1_b, A);
    k_fwd<<<dim3(16384), dim3(256), 0, stream>>>(A, w_ll, LL, HSr, HSi);
    k_mlp<<<dim3(6144), dim3(256), 0, stream>>>(HSr, HSi, w1, w2, b1, b2);
    k_inv<<<dim3(16384), dim3(256), 0, stream>>>(LL, HSr, HSi, Y);
    k_addt<<<dim3(4096), dim3(256), 0, stream>>>(Y, x, out);
    k_leff1<<<dim3(8192), dim3(256), 0, stream>>>(out, ln2_g, ln2_b, lin1_w, lin1_b, H1);
    k_leff2<<<dim3(16384), dim3(256), 0, stream>>>(H1, dw_w, dw_b, lin2_w, lin2_b, out);
}

// Round 2
// 1611.251 us; speedup vs baseline: 1.2971x; 1.2971x over previous
//
#include <hip/hip_runtime.h>
#include <math.h>

#define ISQ2 0.70710678118654752440f

static __device__ __constant__ float H0c[13] = {
    -0.0017578f, 0.0f, 0.0222656f, -0.046875f, -0.0482422f, 0.296875f,
    0.5554688f, 0.296875f, -0.0482422f, -0.046875f, 0.0222656f, 0.0f, -0.0017578f};
static __device__ __constant__ float H1c[19] = {
    -7.06e-05f, 0.0f, 0.0013419f, -0.0018834f, -0.0071568f, 0.023856f,
    0.0556431f, -0.0516881f, -0.2997576f, 0.5594308f, -0.2997576f, -0.0516881f,
    0.0556431f, 0.023856f, -0.0071568f, -0.0018834f, 0.0013419f, 0.0f, -7.06e-05f};

__device__ __forceinline__ int refl32(int i) {
    if (i < 0) i = -1 - i;
    if (i > 31) i = 63 - i;
    return i;
}

__device__ __forceinline__ float gelu_exact(float x) {
    return 0.5f * x * (1.0f + erff(x * ISQ2));
}

// ---------------- K1: LN1 + transpose (B,N,C)->(B,C,32,32) ----------------
__global__ __launch_bounds__(256) void k_ln1_t(const float* __restrict__ x,
                                               const float* __restrict__ g,
                                               const float* __restrict__ be,
                                               float* __restrict__ A) {
    __shared__ float sx[64][65];
    __shared__ float rs[64][4], rq[64][4];
    __shared__ float sm[64], sv[64];
    int b = blockIdx.x >> 4;
    int n0 = (blockIdx.x & 15) << 6;
    int tid = threadIdx.x;
    const float* xp = x + ((size_t)b * 1024 + n0) * 64;
#pragma unroll
    for (int rep = 0; rep < 16; ++rep) {
        int idx = rep * 256 + tid;
        sx[idx >> 6][idx & 63] = xp[idx];
    }
    __syncthreads();
    {
        int i = tid >> 2, q = tid & 3;
        float s = 0.f, ss = 0.f;
#pragma unroll
        for (int d = 0; d < 16; ++d) {
            float v = sx[i][q * 16 + d];
            s += v; ss += v * v;
        }
        rs[i][q] = s; rq[i][q] = ss;
    }
    __syncthreads();
    if (tid < 64) {
        float s = rs[tid][0] + rs[tid][1] + rs[tid][2] + rs[tid][3];
        float ss = rq[tid][0] + rq[tid][1] + rq[tid][2] + rq[tid][3];
        float m = s * (1.f / 64.f);
        float v = ss * (1.f / 64.f) - m * m;
        sm[tid] = m;
        sv[tid] = rsqrtf(v + 1e-5f);
    }
    __syncthreads();
#pragma unroll
    for (int rep = 0; rep < 16; ++rep) {
        int idx = rep * 256 + tid;
        int c = idx >> 6, i = idx & 63;
        float val = (sx[i][c] - sm[i]) * sv[i] * g[c] + be[c];
        A[((size_t)(b * 64 + c)) * 1024 + n0 + i] = val;
    }
}

// ---------------- K2: forward DTCWT per (b,c) image ----------------
__device__ __forceinline__ float col19(const float (*arr)[33], int h, int w) {
    float s = 0.f;
#pragma unroll
    for (int k = 0; k < 19; ++k) s += H1c[k] * arr[refl32(h + k - 9)][w];
    return s;
}
__device__ __forceinline__ float col13(const float (*arr)[33], int h, int w) {
    float s = 0.f;
#pragma unroll
    for (int k = 0; k < 13; ++k) s += H0c[k] * arr[refl32(h + k - 6)][w];
    return s;
}

__global__ __launch_bounds__(256) void k_fwd(const float* __restrict__ A,
                                             const float* __restrict__ wll,
                                             float* __restrict__ LL,
                                             float* __restrict__ HSr,
                                             float* __restrict__ HSi) {
    __shared__ float sx[32][33], slo[32][33], shi[32][33];
    int bc = blockIdx.x;
    int c = bc & 63;
    int tid = threadIdx.x;
    const float* ap = A + (size_t)bc * 1024;
#pragma unroll
    for (int r = 0; r < 4; ++r) {
        int p = r * 256 + tid;
        sx[p >> 5][p & 31] = ap[p];
    }
    __syncthreads();
#pragma unroll
    for (int r = 0; r < 4; ++r) {
        int p = r * 256 + tid;
        int h = p >> 5, w = p & 31;
        float lo = 0.f, hi = 0.f;
#pragma unroll
        for (int k = 0; k < 13; ++k) lo += H0c[k] * sx[h][refl32(w + k - 6)];
#pragma unroll
        for (int k = 0; k < 19; ++k) hi += H1c[k] * sx[h][refl32(w + k - 9)];
        slo[h][w] = lo;
        shi[h][w] = hi;
    }
    __syncthreads();
    // LL = H0 columns on lo, * w_ll
#pragma unroll
    for (int r = 0; r < 4; ++r) {
        int p = r * 256 + tid;
        int h = p >> 5, w = p & 31;
        float acc = 0.f;
#pragma unroll
        for (int k = 0; k < 13; ++k) acc += H0c[k] * slo[refl32(h + k - 6)][w];
        LL[(size_t)bc * 1024 + p] = acc * wll[c * 1024 + p];
    }
    // subbands via q2c
    {
        int p = tid;  // 0..255
        int i = p >> 4, j = p & 15;
        int h0 = 2 * i, w0 = 2 * j;
        size_t base = (size_t)bc * 1536 + p;
        float a, bb, cc, dd;
        a = col19(slo, h0, w0); bb = col19(slo, h0, w0 + 1);
        cc = col19(slo, h0 + 1, w0); dd = col19(slo, h0 + 1, w0 + 1);
        HSr[base + 0 * 256] = (a - dd) * ISQ2; HSi[base + 0 * 256] = (bb + cc) * ISQ2;
        HSr[base + 5 * 256] = (a + dd) * ISQ2; HSi[base + 5 * 256] = (bb - cc) * ISQ2;
        a = col19(shi, h0, w0); bb = col19(shi, h0, w0 + 1);
        cc = col19(shi, h0 + 1, w0); dd = col19(shi, h0 + 1, w0 + 1);
        HSr[base + 1 * 256] = (a - dd) * ISQ2; HSi[base + 1 * 256] = (bb + cc) * ISQ2;
        HSr[base + 4 * 256] = (a + dd) * ISQ2; HSi[base + 4 * 256] = (bb - cc) * ISQ2;
        a = col13(shi, h0, w0); bb = col13(shi, h0, w0 + 1);
        cc = col13(shi, h0 + 1, w0); dd = col13(shi, h0 + 1, w0 + 1);
        HSr[base + 2 * 256] = (a - dd) * ISQ2; HSi[base + 2 * 256] = (bb + cc) * ISQ2;
        HSr[base + 3 * 256] = (a + dd) * ISQ2; HSi[base + 3 * 256] = (bb - cc) * ISQ2;
    }
}

// ---------------- K3: complex block-diagonal MLP (in-place on HS) ----------------
__global__ __launch_bounds__(256) void k_mlp(float* __restrict__ HSr,
                                             float* __restrict__ HSi,
                                             const float* __restrict__ w1,
                                             const float* __restrict__ w2,
                                             const float* __restrict__ b1,
                                             const float* __restrict__ b2) {
    __shared__ float sr[64][65], si[64][65];
    __shared__ float w1s[2048], w2s[2048], b1s[128], b2s[128];
    int blk = blockIdx.x;  // B*6*4 = 6144
    int b = blk / 24;
    int rem = blk % 24;
    int o = rem >> 2;
    int ij0 = (rem & 3) << 6;
    int tid = threadIdx.x;
    for (int idx = tid; idx < 2048; idx += 256) {
        w1s[idx] = w1[idx];
        w2s[idx] = w2[idx];
    }
    if (tid < 128) { b1s[tid] = b1[tid]; b2s[tid] = b2[tid]; }
#pragma unroll
    for (int rep = 0; rep < 16; ++rep) {
        int idx = rep * 256 + tid;
        int c = idx >> 6, j = idx & 63;
        size_t gi = ((size_t)(b * 64 + c) * 6 + o) * 256 + ij0 + j;
        sr[c][j] = HSr[gi];
        si[c][j] = HSi[gi];
    }
    __syncthreads();
    {
        int j = tid & 63, q = tid >> 6;
        float xr[16], xi[16];
#pragma unroll
        for (int d = 0; d < 16; ++d) {
            xr[d] = sr[q * 16 + d][j];
            xi[d] = si[q * 16 + d][j];
        }
        float r1[16], i1[16];
#pragma unroll
        for (int k = 0; k < 16; ++k) {
            float ar = b1s[q * 16 + k];
            float ai = b1s[64 + q * 16 + k];
#pragma unroll
            for (int d = 0; d < 16; ++d) {
                float wr = w1s[q * 256 + d * 16 + k];
                float wi = w1s[1024 + q * 256 + d * 16 + k];
                ar += xr[d] * wr - xi[d] * wi;
                ai += xr[d] * wi + xi[d] * wr;
            }
            r1[k] = fmaxf(ar, 0.f);
            i1[k] = fmaxf(ai, 0.f);
        }
#pragma unroll
        for (int k = 0; k < 16; ++k) {
            float ar = b2s[q * 16 + k];
            float ai = b2s[64 + q * 16 + k];
#pragma unroll
            for (int d = 0; d < 16; ++d) {
                float wr = w2s[q * 256 + d * 16 + k];
                float wi = w2s[1024 + q * 256 + d * 16 + k];
                ar += r1[d] * wr - i1[d] * wi;
                ai += r1[d] * wi + i1[d] * wr;
            }
            sr[q * 16 + k][j] = ar;
            si[q * 16 + k][j] = ai;
        }
    }
    __syncthreads();
#pragma unroll
    for (int rep = 0; rep < 16; ++rep) {
        int idx = rep * 256 + tid;
        int c = idx >> 6, j = idx & 63;
        size_t gi = ((size_t)(b * 64 + c) * 6 + o) * 256 + ij0 + j;
        HSr[gi] = sr[c][j];
        HSi[gi] = si[c][j];
    }
}

// ---------------- K4: inverse DTCWT per (b,c) -> Y (B,C,N) ----------------
__global__ __launch_bounds__(256) void k_inv(const float* __restrict__ LL,
                                             const float* __restrict__ HSr,
                                             const float* __restrict__ HSi,
                                             float* __restrict__ Y) {
    __shared__ float sll[32][33], slh[32][33], shl[32][33], shh[32][33];
    __shared__ float slo[32][33], shi[32][33];
    int bc = blockIdx.x;
    int tid = threadIdx.x;
    const float* lp = LL + (size_t)bc * 1024;
#pragma unroll
    for (int r = 0; r < 4; ++r) {
        int p = r * 256 + tid;
        sll[p >> 5][p & 31] = lp[p];
    }
    {
        int p = tid;
        int i = p >> 4, j = p & 15;
        int h0 = 2 * i, w0 = 2 * j;
        size_t base = (size_t)bc * 1536 + p;
        float o0r = HSr[base + 0 * 256], o0i = HSi[base + 0 * 256];
        float o1r = HSr[base + 1 * 256], o1i = HSi[base + 1 * 256];
        float o2r = HSr[base + 2 * 256], o2i = HSi[base + 2 * 256];
        float o3r = HSr[base + 3 * 256], o3i = HSi[base + 3 * 256];
        float o4r = HSr[base + 4 * 256], o4i = HSi[base + 4 * 256];
        float o5r = HSr[base + 5 * 256], o5i = HSi[base + 5 * 256];
        slh[h0][w0] = (o0r + o5r) * ISQ2;
        slh[h0][w0 + 1] = (o0i + o5i) * ISQ2;
        slh[h0 + 1][w0] = (o0i - o5i) * ISQ2;
        slh[h0 + 1][w0 + 1] = (o5r - o0r) * ISQ2;
        shl[h0][w0] = (o2r + o3r) * ISQ2;
        shl[h0][w0 + 1] = (o2i + o3i) * ISQ2;
        shl[h0 + 1][w0] = (o2i - o3i) * ISQ2;
        shl[h0 + 1][w0 + 1] = (o3r - o2r) * ISQ2;
        shh[h0][w0] = (o1r + o4r) * ISQ2;
        shh[h0][w0 + 1] = (o1i + o4i) * ISQ2;
        shh[h0 + 1][w0] = (o1i - o4i) * ISQ2;
        shh[h0 + 1][w0 + 1] = (o4r - o1r) * ISQ2;
    }
    __syncthreads();
#pragma unroll
    for (int r = 0; r < 4; ++r) {
        int p = r * 256 + tid;
        int h = p >> 5, w = p & 31;
        float lo = 0.f, hi = 0.f;
#pragma unroll
        for (int k = 0; k < 19; ++k) {
            float g0 = (k & 1) ? H1c[k] : -H1c[k];
            int hh2 = refl32(h + k - 9);
            lo += g0 * sll[hh2][w];
            hi += g0 * shl[hh2][w];
        }
#pragma unroll
        for (int k = 0; k < 13; ++k) {
            float g1 = (k & 1) ? H0c[k] : -H0c[k];
            int hh2 = refl32(h + k - 6);
            lo += g1 * slh[hh2][w];
            hi += g1 * shh[hh2][w];
        }
        slo[h][w] = lo;
        shi[h][w] = hi;
    }
    __syncthreads();
#pragma unroll
    for (int r = 0; r < 4; ++r) {
        int p = r * 256 + tid;
        int h = p >> 5, w = p & 31;
        float y = 0.f;
#pragma unroll
        for (int k = 0; k < 19; ++k) {
            float g0 = (k & 1) ? H1c[k] : -H1c[k];
            y += g0 * slo[h][refl32(w + k - 9)];
        }
#pragma unroll
        for (int k = 0; k < 13; ++k) {
            float g1 = (k & 1) ? H0c[k] : -H0c[k];
            y += g1 * shi[h][refl32(w + k - 6)];
        }
        Y[(size_t)bc * 1024 + p] = y;
    }
}

// ---------------- K4b: X1 = x + Y^T -> d_out (B,N,C) ----------------
__global__ __launch_bounds__(256) void k_addt(const float* __restrict__ Y,
                                              const float* __restrict__ x,
                                              float* __restrict__ out) {
    __shared__ float sy[64][65];
    int b = blockIdx.x >> 4;
    int n0 = (blockIdx.x & 15) << 6;
    int tid = threadIdx.x;
#pragma unroll
    for (int rep = 0; rep < 16; ++rep) {
        int idx = rep * 256 + tid;
        int c = idx >> 6, i = idx & 63;
        sy[c][i] = Y[((size_t)(b * 64 + c)) * 1024 + n0 + i];
    }
    __syncthreads();
#pragma unroll
    for (int rep = 0; rep < 16; ++rep) {
        int idx = rep * 256 + tid;
        int i = idx >> 6, c = idx & 63;
        size_t gi = ((size_t)b * 1024 + n0 + i) * 64 + c;
        out[gi] = x[gi] + sy[c][i];
    }
}

// ---------------- K5: LN2 + lin1 + GELU -> H1 (B,N,256) ----------------
// token-per-lane, scalar (wave-uniform) weights via s_load, activations in LDS
__global__ __launch_bounds__(256) void k_leff1(const float* __restrict__ X1,
                                               const float* __restrict__ g2,
                                               const float* __restrict__ be2,
                                               const float* __restrict__ W1,
                                               const float* __restrict__ B1,
                                               float* __restrict__ H1) {
    __shared__ float xs[256 * 65];
    int tid = threadIdx.x;
    size_t tok = (size_t)blockIdx.x * 256 + tid;
    const float4* xp4 = (const float4*)(X1 + tok * 64);
    float s = 0.f, ss = 0.f;
#pragma unroll
    for (int i = 0; i < 16; ++i) {
        float4 v = xp4[i];
        s += v.x + v.y + v.z + v.w;
        ss += v.x * v.x + v.y * v.y + v.z * v.z + v.w * v.w;
        xs[tid * 65 + 4 * i + 0] = v.x;
        xs[tid * 65 + 4 * i + 1] = v.y;
        xs[tid * 65 + 4 * i + 2] = v.z;
        xs[tid * 65 + 4 * i + 3] = v.w;
    }
    float m = s * (1.f / 64.f);
    float var = ss * (1.f / 64.f) - m * m;
    float rstd = rsqrtf(var + 1e-5f);
    __syncthreads();
    const float4* W1v = (const float4*)W1;   // (64, 256) -> row d has 64 float4
    const float4* B1v = (const float4*)B1;
    float4* H1v = (float4*)(H1 + tok * 256);
#pragma unroll 1
    for (int ch = 0; ch < 4; ++ch) {
        float4 acc[16];
#pragma unroll
        for (int j = 0; j < 16; ++j) acc[j] = B1v[ch * 16 + j];
#pragma unroll 2
        for (int d = 0; d < 64; ++d) {
            float xv = xs[tid * 65 + d];
            float xn = (xv - m) * rstd * g2[d] + be2[d];
#pragma unroll
            for (int j = 0; j < 16; ++j) {
                float4 w = W1v[d * 64 + ch * 16 + j];
                acc[j].x += xn * w.x;
                acc[j].y += xn * w.y;
                acc[j].z += xn * w.z;
                acc[j].w += xn * w.w;
            }
        }
#pragma unroll
        for (int j = 0; j < 16; ++j) {
            float4 a = acc[j];
            a.x = gelu_exact(a.x);
            a.y = gelu_exact(a.y);
            a.z = gelu_exact(a.z);
            a.w = gelu_exact(a.w);
            H1v[ch * 16 + j] = a;
        }
    }
}

// ---------------- K6: dwconv3x3 + GELU + lin2 + bias + residual -> out ----------
// token-per-lane; H1 staged per 32-hid chunk in conflict-free LDS tile;
// scalar weights; 64 persistent accumulators; fused residual.
__global__ __launch_bounds__(256) void k_leff2(const float* __restrict__ H1,
                                               const float* __restrict__ DW,
                                               const float* __restrict__ DB,
                                               const float* __restrict__ W2,
                                               const float* __restrict__ B2,
                                               float* __restrict__ out) {
    __shared__ float tile[32 * 341];  // [hid32][r10*34+w], plane stride 341 (≡21 mod 32)
    int tid = threadIdx.x;
    int b = blockIdx.x >> 2;
    int strip = blockIdx.x & 3;       // 8 image rows per strip
    int wave = tid >> 6, lane = tid & 63;
    int rowpair = wave * 2 + (lane >> 5);   // 0..7 within strip
    int w = lane & 31;
    int h_img = strip * 8 + rowpair;
    size_t tok = (size_t)b * 1024 + h_img * 32 + w;

    float4 acc[16];
#pragma unroll
    for (int j = 0; j < 16; ++j) acc[j] = make_float4(0.f, 0.f, 0.f, 0.f);

    const float4* W2v = (const float4*)W2;  // (256, 64) -> row hid has 16 float4
#pragma unroll 1
    for (int ch = 0; ch < 8; ++ch) {
        __syncthreads();
        // stage H1[strip rows -1..8][w -1..32][hid ch*32..+31] with zero halo
        for (int idx = tid; idx < 10880; idx += 256) {
            int hid_l = idx & 31;
            int rest = idx >> 5;           // 0..339
            int r = rest / 34;
            int wt = rest - r * 34;
            int hr = strip * 8 - 1 + r;
            int wi = wt - 1;
            float v = 0.f;
            if (hr >= 0 && hr < 32 && wi >= 0 && wi < 32)
                v = H1[((size_t)b * 1024 + hr * 32 + wi) * 256 + ch * 32 + hid_l];
            tile[hid_l * 341 + rest] = v;
        }
        __syncthreads();
#pragma unroll 2
        for (int hid_l = 0; hid_l < 32; ++hid_l) {
            int hid = ch * 32 + hid_l;
            const float* tp = &tile[hid_l * 341 + rowpair * 34 + w];
            float g = 0.f;
#pragma unroll
            for (int dr = 0; dr < 3; ++dr) {
#pragma unroll
                for (int dwx = 0; dwx < 3; ++dwx) {
                    g += tp[dr * 34 + dwx] * DW[hid * 9 + dr * 3 + dwx];
                }
            }
            g = gelu_exact(g + DB[hid]);
#pragma unroll
            for (int j = 0; j < 16; ++j) {
                float4 w4 = W2v[hid * 16 + j];
                acc[j].x += g * w4.x;
                acc[j].y += g * w4.y;
                acc[j].z += g * w4.z;
                acc[j].w += g * w4.w;
            }
        }
    }
    const float4* B2v = (const float4*)B2;
    float4* outv = (float4*)(out + tok * 64);
#pragma unroll
    for (int j = 0; j < 16; ++j) {
        float4 o = outv[j];
        float4 b4 = B2v[j];
        o.x += acc[j].x + b4.x;
        o.y += acc[j].y + b4.y;
        o.z += acc[j].z + b4.z;
        o.w += acc[j].w + b4.w;
        outv[j] = o;
    }
}

extern "C" void kernel_launch(void* const* d_in, const int* in_sizes, int n_in,
                              void* d_out, int out_size, void* d_ws, size_t ws_size,
                              hipStream_t stream) {
    const float* x = (const float*)d_in[0];
    const float* ln1_g = (const float*)d_in[1];
    const float* ln1_b = (const float*)d_in[2];
    const float* w_ll = (const float*)d_in[3];
    const float* w1 = (const float*)d_in[4];
    const float* w2 = (const float*)d_in[5];
    const float* b1 = (const float*)d_in[6];
    const float* b2 = (const float*)d_in[7];
    const float* ln2_g = (const float*)d_in[8];
    const float* ln2_b = (const float*)d_in[9];
    const float* lin1_w = (const float*)d_in[10];
    const float* lin1_b = (const float*)d_in[11];
    const float* dw_w = (const float*)d_in[12];
    const float* dw_b = (const float*)d_in[13];
    const float* lin2_w = (const float*)d_in[14];
    const float* lin2_b = (const float*)d_in[15];
    float* out = (float*)d_out;
    char* ws = (char*)d_ws;

    float* A = (float*)ws;
    float* HSr = (float*)(ws + 67108864);
    float* HSi = (float*)(ws + 167772160);
    float* LL = out;
    float* Y = A;
    float* H1 = (float*)ws;

    k_ln1_t<<<dim3(4096), dim3(256), 0, stream>>>(x, ln1_g, ln1_b, A);
    k_fwd<<<dim3(16384), dim3(256), 0, stream>>>(A, w_ll, LL, HSr, HSi);
    k_mlp<<<dim3(6144), dim3(256), 0, stream>>>(HSr, HSi, w1, w2, b1, b2);
    k_inv<<<dim3(16384), dim3(256), 0, stream>>>(LL, HSr, HSi, Y);
    k_addt<<<dim3(4096), dim3(256), 0, stream>>>(Y, x, out);
    k_leff1<<<dim3(1024), dim3(256), 0, stream>>>(out, ln2_g, ln2_b, lin1_w, lin1_b, H1);
    k_leff2<<<dim3(1024), dim3(256), 0, stream>>>(H1, dw_w, dw_b, lin2_w, lin2_b, out);
}